// Round 11
// baseline (150.177 us; speedup 1.0000x reference)
//
#include <hip/hip_runtime.h>
#include <hip/hip_bf16.h>

// Flash attention fwd, masked, fp32 I/O, bf16 MFMA compute.
// n=8 heads, q=s=4096, d=v=64.
// Round 11: 32x32x16 MFMA restructure (2x FLOP per LDS byte vs 16x16x32).
// S^T = K·Q^T per 32x32 tile (lane owns one q-column, q=lane&31);
// PV computes O^T = V^T·P^T. 8 waves = 4 q-tiles(32) x 2 s-halves(32) of
// each 64-s chunk; K/V staged ONCE per chunk (shared by both halves);
// per-wave (m,l,O) over its s-half, merged in LDS at the end.
// Keeps: dist-2 reg prefetch, LDS-only barrier, defer-max, setprio,
// mask-dtype template, head-per-XCD grid.

#define NHEADS 8
#define QLEN   4096
#define SLEN   4096
#define DDIM   64
#define VDIM   64
#define SBLK   64
#define QBLK   128
#define NCHUNK (SLEN / SBLK)

typedef __bf16          bf16x4 __attribute__((ext_vector_type(4)));
typedef __bf16          bf16x8 __attribute__((ext_vector_type(8)));
typedef float           f32x4  __attribute__((ext_vector_type(4)));
typedef float           f32x16 __attribute__((ext_vector_type(16)));
typedef unsigned int    u32x4  __attribute__((ext_vector_type(4)));
typedef unsigned short  u16x4  __attribute__((ext_vector_type(4)));

#define KSWZ(s) (((s) & 7) << 4)
#define VSWZ(v) ((((v) >> 2) & 7) << 4)
#define PSWZ(q) (((q) & 3) << 4)
#define CLAMPC(c) ((c) < NCHUNK ? (c) : NCHUNK - 1)

// LDS-only barrier: drain LDS ops, barrier, fence scheduler (rule #18).
#define LDS_BARRIER() do {                                          \
  asm volatile("s_waitcnt lgkmcnt(0)" ::: "memory");                \
  __builtin_amdgcn_s_barrier();                                     \
  __builtin_amdgcn_sched_barrier(0);                                \
} while (0)

__device__ __forceinline__ f32x16 zero16() {
  f32x16 z;
#pragma unroll
  for (int i = 0; i < 16; ++i) z[i] = 0.f;
  return z;
}

// ---------------- in-kernel mask dtype detection ----------------
// i32 {0,1}: bytes 1,2 of every word zero -> 1.
// f32 {0,1.0f}: byte 0 of every word zero (0x3F800000 LE) -> 2.
// u8 bool: neither -> 0. Uniform across all lanes/waves/blocks.
__device__ __forceinline__ int detect_mfmt(const unsigned char* __restrict__ M) {
  const int lane = threadIdx.x & 63;
  u32x4 w = *((const u32x4*)M + lane);
  unsigned o = w[0] | w[1] | w[2] | w[3];
  unsigned comb = ((o & 0x00FFFF00u) ? 1u : 0u) | ((o & 0x000000FFu) ? 2u : 0u);
  comb |= __shfl_xor((int)comb, 1);  comb |= __shfl_xor((int)comb, 2);
  comb |= __shfl_xor((int)comb, 4);  comb |= __shfl_xor((int)comb, 8);
  comb |= __shfl_xor((int)comb, 16); comb |= __shfl_xor((int)comb, 32);
  return ((comb & 1u) == 0u) ? 1 : (((comb & 2u) == 0u) ? 2 : 0);
}

template<bool U8>
__global__ __launch_bounds__(512, 2)
void attn_fwd(const float* __restrict__ Qg, const float* __restrict__ Kg,
              const float* __restrict__ Vg, const unsigned char* __restrict__ Mg,
              float* __restrict__ Og)
{
  __shared__ __align__(16) unsigned short Ksh[2][64 * 64];   // [buf][s][d], KSWZ rows
  __shared__ __align__(16) unsigned short Vsh[2][64 * 64];   // [buf][v][s], VSWZ rows
  __shared__ __align__(16) unsigned short Psh[8][32 * 32];   // per wave [q][s], PSWZ rows
  __shared__ __align__(16) float mO[4][32][68];              // merge: [qtile][q][v] (pad 68)
  __shared__            float mM[4][2][32];                  // merge: m,l per qtile,q

  {
    const int mfmt = detect_mfmt(Mg);
    if (U8 ? (mfmt != 0) : (mfmt == 0)) return;   // other instantiation handles it
  }

  const int tid   = threadIdx.x;
  const int wave  = tid >> 6;
  const int lane  = tid & 63;
  const int qtile = wave & 3;     // q sub-tile (32 q) this wave owns
  const int shalf = wave >> 2;    // s-half (32 s of each 64-s chunk)
  const int lq    = lane & 31;    // lane's q column within the tile
  const int h     = lane >> 5;    // lane half (k-group / row-group selector)

  const int head = blockIdx.x;    // grid (8, 32): linear id % 8 == head -> one XCD per head
  const int qblk = blockIdx.y;

  const float* Qp = Qg + ((size_t)head * QLEN + (size_t)qblk * QBLK) * DDIM;
  const float* Kp = Kg + (size_t)head * SLEN * DDIM;
  const float* Vp = Vg + (size_t)head * SLEN * VDIM;
  float* Op = Og + ((size_t)head * QLEN + (size_t)qblk * QBLK) * DDIM;

  // ---- Q fragments (B-operand: col q = lq, k = 8h + i + 16kd), pre-scaled ----
  const float QSCALE = 0.125f * 1.44269504f;
  const int qrow = qtile * 32 + lq;
  bf16x8 qf[4];
#pragma unroll
  for (int kd = 0; kd < 4; ++kd) {
    const float* qp = Qp + (size_t)qrow * DDIM + 16 * kd + 8 * h;
    f32x4 a = *(const f32x4*)qp;
    f32x4 b = *(const f32x4*)(qp + 4);
    bf16x8 t;
#pragma unroll
    for (int j = 0; j < 4; ++j) { t[j] = (__bf16)(a[j] * QSCALE); t[4 + j] = (__bf16)(b[j] * QSCALE); }
    qf[kd] = t;
  }

  const size_t mbase = ((size_t)head * QLEN + (size_t)qblk * QBLK + qrow) * SLEN
                     + (size_t)shalf * 32;
  const unsigned char* mrow8  = Mg + mbase;
  const unsigned*      mrow32 = (const unsigned*)Mg + mbase;

  f32x16 oacc[2];
  oacc[0] = zero16(); oacc[1] = zero16();
  float m_run = -INFINITY;
  float l_run = 0.f;

  // two named prefetch reg sets (rule #20)
  f32x4 kpA[2], vpA[2], kpB[2], vpB[2];
  unsigned m8A[4],  m8B[4];     // only the U8 set is live (template DCE)
  u32x4    m32A[4], m32B[4];

  // 512 threads stage the 64x64 chunk: srow=(tid>>4)+32it, d0=(tid&15)*4
#define PREFETCH_KV(C, KP, VP)                                                 \
  _Pragma("unroll")                                                            \
  for (int it = 0; it < 2; ++it) {                                             \
    int srow = (tid >> 4) + it * 32;                                           \
    int d0   = (tid & 15) * 4;                                                 \
    size_t gs = (size_t)(CLAMPC(C) * SBLK + srow);                             \
    KP[it] = *(const f32x4*)(Kp + gs * DDIM + d0);                             \
    VP[it] = *(const f32x4*)(Vp + gs * VDIM + d0);                             \
  }

#define WRITE_KV(BUF, KP, VP)                                                  \
  _Pragma("unroll")                                                            \
  for (int it = 0; it < 2; ++it) {                                             \
    int srow = (tid >> 4) + it * 32;                                           \
    int d0   = (tid & 15) * 4;                                                 \
    bf16x4 kb;                                                                 \
    _Pragma("unroll") for (int j = 0; j < 4; ++j) kb[j] = (__bf16)KP[it][j];   \
    int koff = (srow * 128 + d0 * 2) ^ KSWZ(srow);                             \
    *(u16x4*)((char*)Ksh[BUF] + koff) = __builtin_bit_cast(u16x4, kb);         \
    _Pragma("unroll")                                                          \
    for (int j = 0; j < 4; ++j) {                                              \
      int v = d0 + j;                                                          \
      unsigned short b = __builtin_bit_cast(unsigned short, (__bf16)VP[it][j]); \
      int voff = (v * 128 + srow * 2) ^ VSWZ(v);                               \
      *(unsigned short*)((char*)Vsh[BUF] + voff) = b;                          \
    }                                                                          \
  }

  // lane's mask words: q=qrow fixed; word st covers s = 8st+4h+(0..3) of this s-half
#define LOAD_MASK(M8, M32, C)                                                  \
  if constexpr (U8) {                                                          \
    _Pragma("unroll")                                                          \
    for (int st = 0; st < 4; ++st)                                             \
      M8[st] = *(const unsigned*)(mrow8 + (size_t)CLAMPC(C) * SBLK + 8 * st + 4 * h); \
  } else {                                                                     \
    _Pragma("unroll")                                                          \
    for (int st = 0; st < 4; ++st)                                             \
      M32[st] = *(const u32x4*)(mrow32 + (size_t)CLAMPC(C) * SBLK + 8 * st + 4 * h); \
  }

#define CHUNK_BODY(C, CUR, KPF, VPF, KPW, VPW, M8U, M32U) {                    \
  PREFETCH_KV((C) + 2, KPF, VPF);                                              \
  /* QK^T: one 32x32 S^T tile (A = K rows s, B = Q^T), k = d in 4 steps */     \
  f32x16 sacc = zero16();                                                      \
  __builtin_amdgcn_s_setprio(1);                                               \
  _Pragma("unroll")                                                            \
  for (int kd = 0; kd < 4; ++kd) {                                             \
    int srow = shalf * 32 + lq;                                                \
    int off = (srow * 128 + (32 * kd + 16 * h)) ^ KSWZ(srow);                  \
    bf16x8 kf = *(const bf16x8*)((const char*)Ksh[CUR] + off);                 \
    sacc = __builtin_amdgcn_mfma_f32_32x32x16_bf16(kf, qf[kd], sacc, 0, 0, 0); \
  }                                                                            \
  __builtin_amdgcn_s_setprio(0);                                               \
  /* mask + max (lane: q=qrow; reg=4st+r -> s_local = 8st+4h+r) */             \
  float vals[4][4];                                                            \
  float mloc = -INFINITY;                                                      \
  _Pragma("unroll")                                                            \
  for (int st = 0; st < 4; ++st) {                                             \
    bool keep[4];                                                              \
    if constexpr (U8) {                                                        \
      _Pragma("unroll")                                                        \
      for (int r = 0; r < 4; ++r) keep[r] = ((M8U[st] >> (8 * r)) & 0xFFu) != 0u; \
    } else {                                                                   \
      _Pragma("unroll")                                                        \
      for (int r = 0; r < 4; ++r) keep[r] = M32U[st][r] != 0u;                 \
    }                                                                          \
    _Pragma("unroll")                                                          \
    for (int r = 0; r < 4; ++r) {                                              \
      float v = keep[r] ? sacc[4 * st + r] : -1.0e9f;                          \
      vals[st][r] = v;                                                         \
      mloc = fmaxf(mloc, v);                                                   \
    }                                                                          \
  }                                                                            \
  LOAD_MASK(M8U, M32U, (C) + 2);   /* reload same set for chunk C+2 */         \
  mloc = fmaxf(mloc, __shfl_xor(mloc, 32));                                    \
  /* defer-max: rescale only if some row's max grew by > 8 (log2 domain) */    \
  if (!__all(mloc <= m_run + 8.0f)) {                                          \
    float m_new = fmaxf(m_run, mloc);                                          \
    float alpha = __builtin_amdgcn_exp2f(m_run - m_new);                       \
    l_run *= alpha;                                                            \
    _Pragma("unroll")                                                          \
    for (int vt = 0; vt < 2; ++vt) {                                           \
      _Pragma("unroll")                                                        \
      for (int r = 0; r < 16; ++r) oacc[vt][r] *= alpha;                       \
    }                                                                          \
    m_run = m_new;                                                             \
  }                                                                            \
  float lsum = 0.f;                                                            \
  _Pragma("unroll")                                                            \
  for (int st = 0; st < 4; ++st) {                                             \
    bf16x4 pb;                                                                 \
    _Pragma("unroll")                                                          \
    for (int r = 0; r < 4; ++r) {                                              \
      float p = __builtin_amdgcn_exp2f(vals[st][r] - m_run);                   \
      lsum += p;                                                               \
      pb[r] = (__bf16)p;                                                       \
    }                                                                          \
    int poff = (lq * 64 + (16 * st + 8 * h)) ^ PSWZ(lq);                       \
    *(unsigned long long*)((char*)Psh[wave] + poff) =                          \
        __builtin_bit_cast(unsigned long long, pb);                            \
  }                                                                            \
  lsum += __shfl_xor(lsum, 32);                                                \
  l_run += lsum;                                                               \
  /* PV: O^T += V^T·P^T over this wave's 32 s (2 k-steps of 16) */             \
  __builtin_amdgcn_s_setprio(1);                                               \
  _Pragma("unroll")                                                            \
  for (int ks2 = 0; ks2 < 2; ++ks2) {                                          \
    int poff = (lq * 64 + (32 * ks2 + 16 * h)) ^ PSWZ(lq);                     \
    bf16x8 pf = *(const bf16x8*)((const char*)Psh[wave] + poff);               \
    _Pragma("unroll")                                                          \
    for (int vt = 0; vt < 2; ++vt) {                                           \
      int vrow = vt * 32 + lq;                                                 \
      int voff = (vrow * 128 + (64 * shalf + 32 * ks2 + 16 * h)) ^ VSWZ(vrow); \
      bf16x8 vf = *(const bf16x8*)((const char*)Vsh[CUR] + voff);              \
      oacc[vt] = __builtin_amdgcn_mfma_f32_32x32x16_bf16(vf, pf, oacc[vt], 0, 0, 0); \
    }                                                                          \
  }                                                                            \
  __builtin_amdgcn_s_setprio(0);                                               \
  WRITE_KV((CUR) ^ 1, KPW, VPW);   /* drains loads issued one body ago */      \
  LDS_BARRIER();                                                               \
}

  // prologue: chunk0 -> setA -> buf0; chunk1 -> setB (left in flight)
  PREFETCH_KV(0, kpA, vpA);
  LOAD_MASK(m8A, m32A, 0);
  PREFETCH_KV(1, kpB, vpB);
  LOAD_MASK(m8B, m32B, 1);
  WRITE_KV(0, kpA, vpA);
  LDS_BARRIER();

  for (int cc = 0; cc < NCHUNK; cc += 2) {
    CHUNK_BODY(cc,     0, kpA, vpA, kpB, vpB, m8A, m32A);
    CHUNK_BODY(cc + 1, 1, kpB, vpB, kpA, vpA, m8B, m32B);
  }

  // ---- merge the two s-halves (wave pairs qtile,shalf=0/1) via LDS ----
  // oacc reg -> v = (reg&3) + 8*(reg>>2) + 4h + 32vt (col q = lq fixed)
  if (shalf == 1) {
#pragma unroll
    for (int vt = 0; vt < 2; ++vt) {
#pragma unroll
      for (int st = 0; st < 4; ++st) {
        int v0 = 32 * vt + 8 * st + 4 * h;
        f32x4 o;
#pragma unroll
        for (int r = 0; r < 4; ++r) o[r] = oacc[vt][4 * st + r];
        *(f32x4*)&mO[qtile][lq][v0] = o;
      }
    }
    if (h == 0) {
      mM[qtile][0][lq] = m_run;
      mM[qtile][1][lq] = l_run;
    }
  }
  LDS_BARRIER();
  if (shalf == 0) {
    float m1 = mM[qtile][0][lq];
    float l1 = mM[qtile][1][lq];
    float mm = fmaxf(m_run, m1);
    float a0 = __builtin_amdgcn_exp2f(m_run - mm);
    float a1 = __builtin_amdgcn_exp2f(m1 - mm);
    float inv = 1.0f / (l_run * a0 + l1 * a1);
    float* orow = Op + (size_t)qrow * VDIM;
#pragma unroll
    for (int vt = 0; vt < 2; ++vt) {
#pragma unroll
      for (int st = 0; st < 4; ++st) {
        int v0 = 32 * vt + 8 * st + 4 * h;
        f32x4 o1 = *(const f32x4*)&mO[qtile][lq][v0];
        f32x4 o;
#pragma unroll
        for (int r = 0; r < 4; ++r) o[r] = (oacc[vt][4 * st + r] * a0 + o1[r] * a1) * inv;
        *(f32x4*)(orow + v0) = o;
      }
    }
  }
#undef PREFETCH_KV
#undef WRITE_KV
#undef LOAD_MASK
#undef CHUNK_BODY
}

extern "C" void kernel_launch(void* const* d_in, const int* in_sizes, int n_in,
                              void* d_out, int out_size, void* d_ws, size_t ws_size,
                              hipStream_t stream) {
  const float* Qg = (const float*)d_in[0];
  const float* Kg = (const float*)d_in[1];
  const float* Vg = (const float*)d_in[2];
  const unsigned char* Mg = (const unsigned char*)d_in[3];
  float* Og = (float*)d_out;

  dim3 grid(NHEADS, QLEN / QBLK);   // 256 blocks; linear id % 8 == head -> head-per-XCD
  dim3 block(512);
  attn_fwd<true ><<<grid, block, 0, stream>>>(Qg, Kg, Vg, Mg, Og);   // u8 bool mask
  attn_fwd<false><<<grid, block, 0, stream>>>(Qg, Kg, Vg, Mg, Og);   // i32/f32 mask
}

// Round 12
// 149.818 us; speedup vs baseline: 1.0024x; 1.0024x over previous
//
#include <hip/hip_runtime.h>
#include <hip/hip_bf16.h>

// Flash attention fwd, masked, fp32 I/O, bf16 MFMA compute.
// n=8 heads, q=s=4096, d=v=64.
// Round 12: r11 base (32x32x16 MFMA, dist-2 KV reg prefetch, LDS-only
// barrier) + MASK THROUGH LDS: the per-lane mask gather (4 dword loads x 64
// lanes x 64 distinct 4KB-strided rows = ~2K cy/chunk of TA address
// serialization, constant across r6-r11) is replaced by one coalesced
// dwordx4 per thread into a double-buffered LDS tile (row stride 68B: 17
// dwords, 17 coprime 32 -> conflict-free per-lane reads).

#define NHEADS 8
#define QLEN   4096
#define SLEN   4096
#define DDIM   64
#define VDIM   64
#define SBLK   64
#define QBLK   128
#define NCHUNK (SLEN / SBLK)
#define MROWB  68        // mask LDS row stride (bytes)

typedef __bf16          bf16x4 __attribute__((ext_vector_type(4)));
typedef __bf16          bf16x8 __attribute__((ext_vector_type(8)));
typedef float           f32x4  __attribute__((ext_vector_type(4)));
typedef float           f32x16 __attribute__((ext_vector_type(16)));
typedef unsigned int    u32x4  __attribute__((ext_vector_type(4)));
typedef unsigned short  u16x4  __attribute__((ext_vector_type(4)));

#define KSWZ(s) (((s) & 7) << 4)
#define VSWZ(v) ((((v) >> 2) & 7) << 4)
#define PSWZ(q) (((q) & 3) << 4)
#define CLAMPC(c) ((c) < NCHUNK ? (c) : NCHUNK - 1)

// LDS-only barrier: drain LDS ops, barrier, fence scheduler (rule #18).
#define LDS_BARRIER() do {                                          \
  asm volatile("s_waitcnt lgkmcnt(0)" ::: "memory");                \
  __builtin_amdgcn_s_barrier();                                     \
  __builtin_amdgcn_sched_barrier(0);                                \
} while (0)

__device__ __forceinline__ f32x16 zero16() {
  f32x16 z;
#pragma unroll
  for (int i = 0; i < 16; ++i) z[i] = 0.f;
  return z;
}

// ---------------- in-kernel mask dtype detection ----------------
// i32 {0,1}: bytes 1,2 of every word zero -> 1.
// f32 {0,1.0f}: byte 0 of every word zero (0x3F800000 LE) -> 2.
// u8 bool: neither -> 0. Uniform across all lanes/waves/blocks.
__device__ __forceinline__ int detect_mfmt(const unsigned char* __restrict__ M) {
  const int lane = threadIdx.x & 63;
  u32x4 w = *((const u32x4*)M + lane);
  unsigned o = w[0] | w[1] | w[2] | w[3];
  unsigned comb = ((o & 0x00FFFF00u) ? 1u : 0u) | ((o & 0x000000FFu) ? 2u : 0u);
  comb |= __shfl_xor((int)comb, 1);  comb |= __shfl_xor((int)comb, 2);
  comb |= __shfl_xor((int)comb, 4);  comb |= __shfl_xor((int)comb, 8);
  comb |= __shfl_xor((int)comb, 16); comb |= __shfl_xor((int)comb, 32);
  return ((comb & 1u) == 0u) ? 1 : (((comb & 2u) == 0u) ? 2 : 0);
}

template<bool U8>
__global__ __launch_bounds__(512, 2)
void attn_fwd(const float* __restrict__ Qg, const float* __restrict__ Kg,
              const float* __restrict__ Vg, const unsigned char* __restrict__ Mg,
              float* __restrict__ Og)
{
  __shared__ __align__(16) unsigned short Ksh[2][64 * 64];   // [buf][s][d], KSWZ rows
  __shared__ __align__(16) unsigned short Vsh[2][64 * 64];   // [buf][v][s], VSWZ rows
  __shared__ __align__(16) unsigned short Psh[8][32 * 32];   // per wave [q][s], PSWZ rows
  __shared__ __align__(16) unsigned char Msh[2][128 * MROWB];// [buf][q][64B mask], stride 68
  __shared__ __align__(16) float mO[4][32][68];              // merge: [qtile][q][v] (pad 68)
  __shared__            float mM[4][2][32];                  // merge: m,l per qtile,q

  {
    const int mfmt = detect_mfmt(Mg);
    if (U8 ? (mfmt != 0) : (mfmt == 0)) return;   // other instantiation handles it
  }

  const int tid   = threadIdx.x;
  const int wave  = tid >> 6;
  const int lane  = tid & 63;
  const int qtile = wave & 3;     // q sub-tile (32 q) this wave owns
  const int shalf = wave >> 2;    // s-half (32 s of each 64-s chunk)
  const int lq    = lane & 31;    // lane's q column within the tile
  const int h     = lane >> 5;    // lane half (k-group / row-group selector)

  const int head = blockIdx.x;    // grid (8, 32): linear id % 8 == head -> one XCD per head
  const int qblk = blockIdx.y;

  const float* Qp = Qg + ((size_t)head * QLEN + (size_t)qblk * QBLK) * DDIM;
  const float* Kp = Kg + (size_t)head * SLEN * DDIM;
  const float* Vp = Vg + (size_t)head * SLEN * VDIM;
  float* Op = Og + ((size_t)head * QLEN + (size_t)qblk * QBLK) * DDIM;
  // block's mask base (row 0 of this q-block)
  const unsigned char* Mblk = Mg + ((size_t)head * QLEN + (size_t)qblk * QBLK) * SLEN;

  // ---- Q fragments (B-operand: col q = lq, k = 8h + i + 16kd), pre-scaled ----
  const float QSCALE = 0.125f * 1.44269504f;
  const int qrow = qtile * 32 + lq;
  bf16x8 qf[4];
#pragma unroll
  for (int kd = 0; kd < 4; ++kd) {
    const float* qp = Qp + (size_t)qrow * DDIM + 16 * kd + 8 * h;
    f32x4 a = *(const f32x4*)qp;
    f32x4 b = *(const f32x4*)(qp + 4);
    bf16x8 t;
#pragma unroll
    for (int j = 0; j < 4; ++j) { t[j] = (__bf16)(a[j] * QSCALE); t[4 + j] = (__bf16)(b[j] * QSCALE); }
    qf[kd] = t;
  }

  // i32/f32 fallback path keeps the per-lane gather
  const size_t mbase32 = ((size_t)head * QLEN + (size_t)qblk * QBLK + qrow) * SLEN
                       + (size_t)shalf * 32;
  const unsigned* mrow32 = (const unsigned*)Mg + mbase32;

  f32x16 oacc[2];
  oacc[0] = zero16(); oacc[1] = zero16();
  float m_run = -INFINITY;
  float l_run = 0.f;

  // named prefetch reg sets (rule #20)
  f32x4 kpA[2], vpA[2], kpB[2], vpB[2];
  u32x4 mpA, mpB;               // U8: coalesced mask chunk (1 dwordx4/thread)
  u32x4 m32A[4], m32B[4];       // !U8 gather sets (template DCE)

  // 512 threads stage the 64x64 K/V chunk: srow=(tid>>4)+32it, d0=(tid&15)*4
#define PREFETCH_KV(C, KP, VP)                                                 \
  _Pragma("unroll")                                                            \
  for (int it = 0; it < 2; ++it) {                                             \
    int srow = (tid >> 4) + it * 32;                                           \
    int d0   = (tid & 15) * 4;                                                 \
    size_t gs = (size_t)(CLAMPC(C) * SBLK + srow);                             \
    KP[it] = *(const f32x4*)(Kp + gs * DDIM + d0);                             \
    VP[it] = *(const f32x4*)(Vp + gs * VDIM + d0);                             \
  }

#define WRITE_KV(BUF, KP, VP)                                                  \
  _Pragma("unroll")                                                            \
  for (int it = 0; it < 2; ++it) {                                             \
    int srow = (tid >> 4) + it * 32;                                           \
    int d0   = (tid & 15) * 4;                                                 \
    bf16x4 kb;                                                                 \
    _Pragma("unroll") for (int j = 0; j < 4; ++j) kb[j] = (__bf16)KP[it][j];   \
    int koff = (srow * 128 + d0 * 2) ^ KSWZ(srow);                             \
    *(u16x4*)((char*)Ksh[BUF] + koff) = __builtin_bit_cast(u16x4, kb);         \
    _Pragma("unroll")                                                          \
    for (int j = 0; j < 4; ++j) {                                              \
      int v = d0 + j;                                                          \
      unsigned short b = __builtin_bit_cast(unsigned short, (__bf16)VP[it][j]); \
      int voff = (v * 128 + srow * 2) ^ VSWZ(v);                               \
      *(unsigned short*)((char*)Vsh[BUF] + voff) = b;                          \
    }                                                                          \
  }

  // U8 mask staging: thread t covers row t>>2, bytes (t&3)*16 of the 64B chunk row.
#define MASK_LOAD_U8(C, MP) {                                                  \
  int r_ = tid >> 2, c_ = (tid & 3) * 16;                                      \
  MP = *(const u32x4*)(Mblk + (size_t)r_ * SLEN + (size_t)CLAMPC(C) * SBLK + c_); \
}
#define MASK_WRITE_U8(BUF, MP) {                                               \
  int r_ = tid >> 2, c_ = (tid & 3) * 16;                                      \
  unsigned* d_ = (unsigned*)(Msh[BUF] + r_ * MROWB + c_);                      \
  d_[0] = MP[0]; d_[1] = MP[1]; d_[2] = MP[2]; d_[3] = MP[3];                  \
}

#define LOAD_MASK32(M32, C)                                                    \
  if constexpr (!U8) {                                                         \
    _Pragma("unroll")                                                          \
    for (int st = 0; st < 4; ++st)                                             \
      M32[st] = *(const u32x4*)(mrow32 + (size_t)CLAMPC(C) * SBLK + 8 * st + 4 * h); \
  }

// Body C: buf[CUR] holds K/V/mask chunk C. (KPW,VPW,MPW) hold chunk C+1 (loaded
// at body C-1) -> written to buf CUR^1 at end. (KPF,VPF,MPF) receive C+2 loads.
#define CHUNK_BODY(C, CUR, KPF, VPF, KPW, VPW, MPF, MPW, M32U) {               \
  PREFETCH_KV((C) + 2, KPF, VPF);                                              \
  if constexpr (U8) { MASK_LOAD_U8((C) + 2, MPF); }                            \
  /* lane's mask words from LDS (row qrow, stride 68 -> conflict-free) */      \
  unsigned mw0, mw1, mw2, mw3;                                                 \
  if constexpr (U8) {                                                          \
    const unsigned char* mr_ = Msh[CUR] + qrow * MROWB + 32 * shalf + 4 * h;   \
    mw0 = *(const unsigned*)(mr_ + 0);                                         \
    mw1 = *(const unsigned*)(mr_ + 8);                                         \
    mw2 = *(const unsigned*)(mr_ + 16);                                        \
    mw3 = *(const unsigned*)(mr_ + 24);                                        \
  }                                                                            \
  /* QK^T: one 32x32 S^T tile (A = K rows s, B = Q^T), k = d in 4 steps */     \
  f32x16 sacc = zero16();                                                      \
  __builtin_amdgcn_s_setprio(1);                                               \
  _Pragma("unroll")                                                            \
  for (int kd = 0; kd < 4; ++kd) {                                             \
    int srow = shalf * 32 + lq;                                                \
    int off = (srow * 128 + (32 * kd + 16 * h)) ^ KSWZ(srow);                  \
    bf16x8 kf = *(const bf16x8*)((const char*)Ksh[CUR] + off);                 \
    sacc = __builtin_amdgcn_mfma_f32_32x32x16_bf16(kf, qf[kd], sacc, 0, 0, 0); \
  }                                                                            \
  __builtin_amdgcn_s_setprio(0);                                               \
  /* mask + max (lane: q=qrow; reg=4st+r -> s_local = 8st+4h+r) */             \
  float vals[4][4];                                                            \
  float mloc = -INFINITY;                                                      \
  _Pragma("unroll")                                                            \
  for (int st = 0; st < 4; ++st) {                                             \
    bool keep[4];                                                              \
    if constexpr (U8) {                                                        \
      unsigned w_ = (st == 0) ? mw0 : (st == 1) ? mw1 : (st == 2) ? mw2 : mw3; \
      _Pragma("unroll")                                                        \
      for (int r = 0; r < 4; ++r) keep[r] = ((w_ >> (8 * r)) & 0xFFu) != 0u;   \
    } else {                                                                   \
      _Pragma("unroll")                                                        \
      for (int r = 0; r < 4; ++r) keep[r] = M32U[st][r] != 0u;                 \
    }                                                                          \
    _Pragma("unroll")                                                          \
    for (int r = 0; r < 4; ++r) {                                              \
      float v = keep[r] ? sacc[4 * st + r] : -1.0e9f;                          \
      vals[st][r] = v;                                                         \
      mloc = fmaxf(mloc, v);                                                   \
    }                                                                          \
  }                                                                            \
  LOAD_MASK32(M32U, (C) + 2);   /* !U8: reload same set for chunk C+2 */       \
  mloc = fmaxf(mloc, __shfl_xor(mloc, 32));                                    \
  /* defer-max: rescale only if some row's max grew by > 8 (log2 domain) */    \
  if (!__all(mloc <= m_run + 8.0f)) {                                          \
    float m_new = fmaxf(m_run, mloc);                                          \
    float alpha = __builtin_amdgcn_exp2f(m_run - m_new);                       \
    l_run *= alpha;                                                            \
    _Pragma("unroll")                                                          \
    for (int vt = 0; vt < 2; ++vt) {                                           \
      _Pragma("unroll")                                                        \
      for (int r = 0; r < 16; ++r) oacc[vt][r] *= alpha;                       \
    }                                                                          \
    m_run = m_new;                                                             \
  }                                                                            \
  float lsum = 0.f;                                                            \
  _Pragma("unroll")                                                            \
  for (int st = 0; st < 4; ++st) {                                             \
    bf16x4 pb;                                                                 \
    _Pragma("unroll")                                                          \
    for (int r = 0; r < 4; ++r) {                                              \
      float p = __builtin_amdgcn_exp2f(vals[st][r] - m_run);                   \
      lsum += p;                                                               \
      pb[r] = (__bf16)p;                                                       \
    }                                                                          \
    int poff = (lq * 64 + (16 * st + 8 * h)) ^ PSWZ(lq);                       \
    *(unsigned long long*)((char*)Psh[wave] + poff) =                          \
        __builtin_bit_cast(unsigned long long, pb);                            \
  }                                                                            \
  lsum += __shfl_xor(lsum, 32);                                                \
  l_run += lsum;                                                               \
  /* PV: O^T += V^T·P^T over this wave's 32 s (2 k-steps of 16) */             \
  __builtin_amdgcn_s_setprio(1);                                               \
  _Pragma("unroll")                                                            \
  for (int ks2 = 0; ks2 < 2; ++ks2) {                                          \
    int poff = (lq * 64 + (32 * ks2 + 16 * h)) ^ PSWZ(lq);                     \
    bf16x8 pf = *(const bf16x8*)((const char*)Psh[wave] + poff);               \
    _Pragma("unroll")                                                          \
    for (int vt = 0; vt < 2; ++vt) {                                           \
      int vrow = vt * 32 + lq;                                                 \
      int voff = (vrow * 128 + (64 * shalf + 32 * ks2 + 16 * h)) ^ VSWZ(vrow); \
      bf16x8 vf = *(const bf16x8*)((const char*)Vsh[CUR] + voff);              \
      oacc[vt] = __builtin_amdgcn_mfma_f32_32x32x16_bf16(vf, pf, oacc[vt], 0, 0, 0); \
    }                                                                          \
  }                                                                            \
  __builtin_amdgcn_s_setprio(0);                                               \
  WRITE_KV((CUR) ^ 1, KPW, VPW);   /* drains loads issued one body ago */      \
  if constexpr (U8) { MASK_WRITE_U8((CUR) ^ 1, MPW); }                         \
  LDS_BARRIER();                                                               \
}

  // prologue: chunk0 -> A -> buf0; chunk1 -> B (left in flight)
  PREFETCH_KV(0, kpA, vpA);
  if constexpr (U8) { MASK_LOAD_U8(0, mpA); }
  LOAD_MASK32(m32A, 0);
  PREFETCH_KV(1, kpB, vpB);
  if constexpr (U8) { MASK_LOAD_U8(1, mpB); }
  LOAD_MASK32(m32B, 1);
  WRITE_KV(0, kpA, vpA);
  if constexpr (U8) { MASK_WRITE_U8(0, mpA); }
  LDS_BARRIER();

  for (int cc = 0; cc < NCHUNK; cc += 2) {
    CHUNK_BODY(cc,     0, kpA, vpA, kpB, vpB, mpA, mpB, m32A);
    CHUNK_BODY(cc + 1, 1, kpB, vpB, kpA, vpA, mpB, mpA, m32B);
  }

  // ---- merge the two s-halves (wave pairs qtile,shalf=0/1) via LDS ----
  // oacc reg -> v = (reg&3) + 8*(reg>>2) + 4h + 32vt (col q = lq fixed)
  if (shalf == 1) {
#pragma unroll
    for (int vt = 0; vt < 2; ++vt) {
#pragma unroll
      for (int st = 0; st < 4; ++st) {
        int v0 = 32 * vt + 8 * st + 4 * h;
        f32x4 o;
#pragma unroll
        for (int r = 0; r < 4; ++r) o[r] = oacc[vt][4 * st + r];
        *(f32x4*)&mO[qtile][lq][v0] = o;
      }
    }
    if (h == 0) {
      mM[qtile][0][lq] = m_run;
      mM[qtile][1][lq] = l_run;
    }
  }
  LDS_BARRIER();
  if (shalf == 0) {
    float m1 = mM[qtile][0][lq];
    float l1 = mM[qtile][1][lq];
    float mm = fmaxf(m_run, m1);
    float a0 = __builtin_amdgcn_exp2f(m_run - mm);
    float a1 = __builtin_amdgcn_exp2f(m1 - mm);
    float inv = 1.0f / (l_run * a0 + l1 * a1);
    float* orow = Op + (size_t)qrow * VDIM;
#pragma unroll
    for (int vt = 0; vt < 2; ++vt) {
#pragma unroll
      for (int st = 0; st < 4; ++st) {
        int v0 = 32 * vt + 8 * st + 4 * h;
        f32x4 o1 = *(const f32x4*)&mO[qtile][lq][v0];
        f32x4 o;
#pragma unroll
        for (int r = 0; r < 4; ++r) o[r] = (oacc[vt][4 * st + r] * a0 + o1[r] * a1) * inv;
        *(f32x4*)(orow + v0) = o;
      }
    }
  }
#undef PREFETCH_KV
#undef WRITE_KV
#undef MASK_LOAD_U8
#undef MASK_WRITE_U8
#undef LOAD_MASK32
#undef CHUNK_BODY
}

extern "C" void kernel_launch(void* const* d_in, const int* in_sizes, int n_in,
                              void* d_out, int out_size, void* d_ws, size_t ws_size,
                              hipStream_t stream) {
  const float* Qg = (const float*)d_in[0];
  const float* Kg = (const float*)d_in[1];
  const float* Vg = (const float*)d_in[2];
  const unsigned char* Mg = (const unsigned char*)d_in[3];
  float* Og = (float*)d_out;

  dim3 grid(NHEADS, QLEN / QBLK);   // 256 blocks; linear id % 8 == head -> head-per-XCD
  dim3 block(512);
  attn_fwd<true ><<<grid, block, 0, stream>>>(Qg, Kg, Vg, Mg, Og);   // u8 bool mask
  attn_fwd<false><<<grid, block, 0, stream>>>(Qg, Kg, Vg, Mg, Og);   // i32/f32 mask
}